// Round 7
// baseline (305.951 us; speedup 1.0000x reference)
//
#include <hip/hip_runtime.h>
#include <hip/hip_fp16.h>

// VGAE on GCN: N=50000, E=1.6M, IN=256, HIDDEN=128, OUT=64.
// Round 17: grouped MFMA-gather + XCD-pinned quarters. Wave = (16-node group,
// quarter). blockIdx.x & 7 selects the XCD (round-robin dispatch); quarter =
// (bid&7)>>1, so each quarter's 3.2MB table lives in ONE XCD pair's L2 (4MiB
// each) -- fixes R16's concurrent-quarter L2 thrash (FETCH 172MB -> ~40MB).
// Per 32-edge chunk: stage rows to LDS (2x global_load_lds 16B/lane, dbuf),
// ds_read_b64_tr_b16 (linear base+8*lane) -> B[32x16] x2; A = 0/1 membership
// flags (compare vs per-lane rs/re through tr-read edge permutation
// pi(8g+j)=4g+(j&3)+16*(j>>2)); 2 MFMA accumulate 16 nodes x 32 feats.
// Counted vmcnt(3) mid-loop; ssrc prefetched nontemporal; NT output stores.

#define IN_DIM 256
#define F1 128   // HIDDEN
#define F2 64    // OUT
#define QF 32    // features per quarter (F1/4)
#define BN 128        // nodes per bucket
#define CAP 4736      // bucket capacity: mean 4096, +10 sigma
#define BIN_EDGES 4096  // edges per binning block (512 thr x 8)

typedef _Float16 f16x8 __attribute__((ext_vector_type(8)));
typedef _Float16 f16x4 __attribute__((ext_vector_type(4)));
typedef float f32x4 __attribute__((ext_vector_type(4)));

static inline int cdiv_i(int a, int b) { return (a + b - 1) / b; }

__device__ static inline uint32_t lds_addr(const void* p) {
    return (uint32_t)(size_t)(const __attribute__((address_space(3))) void*)p;
}

// ---- weight prep: fragment-ordered fp16 buffers ----
__global__ void k_prep_frags(const float* __restrict__ W1,
                             const float* __restrict__ Wmu,
                             const float* __restrict__ Wls,
                             __half* __restrict__ W1frag,
                             __half* __restrict__ Wcfrag) {
    int t = blockIdx.x * blockDim.x + threadIdx.x;
    if (t < 8 * 8 * 64) {
        int lane = t & 63, nt = (t >> 6) & 7, ks = t >> 9;
        int k0 = ks * 32 + ((lane >> 4) << 3);
        int n = nt * 16 + (lane & 15);
#pragma unroll
        for (int j = 0; j < 8; ++j)
            W1frag[(size_t)t * 8 + j] = __float2half(W1[(k0 + j) * F1 + n]);
    } else if (t < 8 * 8 * 64 + 4 * 8 * 64) {
        int u = t - 8 * 8 * 64;
        int lane = u & 63, nt = (u >> 6) & 7, ks = u >> 9;
        int k0 = ks * 32 + ((lane >> 4) << 3);
        int c = nt * 16 + (lane & 15);
        const float* W = (c < F2) ? (Wmu + c) : (Wls + (c - F2));
#pragma unroll
        for (int j = 0; j < 8; ++j)
            Wcfrag[(size_t)u * 8 + j] = __float2half(W[(k0 + j) * F2]);
    }
}

// ---- pass 1: bin edges by dst>>7; packed pair = (dst&127)<<16 | src ----
__global__ __launch_bounds__(512) void k_binning(const int* __restrict__ src,
                                                 const int* __restrict__ dst,
                                                 int* __restrict__ bcur,
                                                 int* __restrict__ pairs, int E) {
    __shared__ int hcnt[512];
    __shared__ int hrank[512];
    __shared__ int hbase[512];
    __shared__ int lbase[512];
    __shared__ int stage[BIN_EDGES];
    __shared__ int gaddr[BIN_EDGES];
    const int tid = threadIdx.x;
    hcnt[tid] = 0; hrank[tid] = 0;
    __syncthreads();
    const int e0 = blockIdx.x * BIN_EDGES;
    int s_[8], d_[8];
#pragma unroll
    for (int it = 0; it < 8; ++it) {
        int e = e0 + it * 512 + tid;
        if (e < E) {
            s_[it] = src[e];
            d_[it] = dst[e];
            atomicAdd(&hcnt[d_[it] >> 7], 1);
        } else {
            d_[it] = -1;
        }
    }
    __syncthreads();
    int v = hcnt[tid];
    lbase[tid] = v;
    __syncthreads();
    for (int ofs = 1; ofs < 512; ofs <<= 1) {
        int add = (tid >= ofs) ? lbase[tid - ofs] : 0;
        __syncthreads();
        lbase[tid] += add;
        __syncthreads();
    }
    int total = lbase[511];
    int excl = lbase[tid] - v;
    __syncthreads();
    lbase[tid] = excl;
    hbase[tid] = v ? atomicAdd(&bcur[tid], v) : 0;
    __syncthreads();
#pragma unroll
    for (int it = 0; it < 8; ++it) {
        if (d_[it] >= 0) {
            int b = d_[it] >> 7;
            int r = atomicAdd(&hrank[b], 1);
            int li = lbase[b] + r;
            stage[li] = ((d_[it] & (BN - 1)) << 16) | s_[it];
            gaddr[li] = b * CAP + hbase[b] + r;
        }
    }
    __syncthreads();
    for (int i = tid; i < total; i += 512)
        pairs[gaddr[i]] = stage[i];
}

// ---- pass 2: per-bucket histogram -> scan -> dinv + [rs,re) + staged ssrc ----
__global__ __launch_bounds__(512) void k_bucket_build(const int* __restrict__ pairs,
                                                      const int* __restrict__ bcur,
                                                      float* __restrict__ dinv,
                                                      int* __restrict__ rs,
                                                      int* __restrict__ re,
                                                      int* __restrict__ ssrc, int N) {
    __shared__ int hist[BN];
    __shared__ int offs[BN];
    __shared__ int stage[CAP];
    const int b = blockIdx.x;
    const int n0 = b * BN;
    const int tid = threadIdx.x;
    const int pbase = b * CAP;
    const int cnt = min(bcur[b], CAP);
    if (tid < BN) hist[tid] = 0;
    __syncthreads();
    for (int e = tid; e < cnt; e += 512)
        atomicAdd(&hist[pairs[pbase + e] >> 16], 1);
    __syncthreads();
    if (tid < BN) offs[tid] = hist[tid];
    __syncthreads();
    for (int ofs = 1; ofs < BN; ofs <<= 1) {
        int add = 0;
        if (tid < BN && tid >= ofs) add = offs[tid - ofs];
        __syncthreads();
        if (tid < BN) offs[tid] += add;
        __syncthreads();
    }
    if (tid < BN) {
        int incl = offs[tid];
        int excl = incl - hist[tid];
        int n = n0 + tid;
        if (n < N) {
            dinv[n] = rsqrtf((float)hist[tid] + 1.0f);   // +1 self-loop
            rs[n] = pbase + excl;
            re[n] = pbase + incl;
        }
        offs[tid] = excl;
    }
    __syncthreads();
    for (int e = tid; e < cnt; e += 512) {
        int p = pairs[pbase + e];
        int idx = atomicAdd(&offs[p >> 16], 1);
        stage[idx] = p & 0xFFFF;
    }
    __syncthreads();
    for (int i = tid; i < cnt; i += 512) ssrc[pbase + i] = stage[i];
}

// ---- GEMM1 MFMA: tq[4][M][32] = fp16( dinv[m] * (x[M,256] @ W1)[m] ) ----
__global__ __launch_bounds__(256) void k_gemm1_mfma(const float* __restrict__ x,
                                                    const __half* __restrict__ W1frag,
                                                    const float* __restrict__ dinv,
                                                    __half* __restrict__ C, int M) {
    const int wave = threadIdx.x >> 6;
    const int lane = threadIdx.x & 63;
    const int m0 = blockIdx.x * 64 + wave * 16;
    if (m0 >= M) return;
    const int q = lane >> 4;
    const int arow = m0 + (lane & 15);
    f32x4 acc[8] = {};
#pragma unroll
    for (int ks = 0; ks < 8; ++ks) {
        const float* ap = x + (size_t)arow * IN_DIM + ks * 32 + q * 8;
        f32x4 f0 = *(const f32x4*)(ap);
        f32x4 f1 = *(const f32x4*)(ap + 4);
        f16x8 a = { (_Float16)f0.x, (_Float16)f0.y, (_Float16)f0.z, (_Float16)f0.w,
                    (_Float16)f1.x, (_Float16)f1.y, (_Float16)f1.z, (_Float16)f1.w };
        const __half* bbase = W1frag + ((size_t)(ks * 8) * 64 + lane) * 8;
#pragma unroll
        for (int nt = 0; nt < 8; ++nt) {
            f16x8 bfrag = *(const f16x8*)(bbase + (size_t)nt * 64 * 8);
            acc[nt] = __builtin_amdgcn_mfma_f32_16x16x32_f16(a, bfrag, acc[nt], 0, 0, 0);
        }
    }
    float dv[4];
#pragma unroll
    for (int r = 0; r < 4; ++r) dv[r] = dinv[m0 + q * 4 + r];
#pragma unroll
    for (int nt = 0; nt < 8; ++nt) {
        int col = nt * 16 + (lane & 15);
        __half* cq = C + (size_t)(col >> 5) * M * QF + (col & 31);
#pragma unroll
        for (int r = 0; r < 4; ++r)
            cq[(size_t)(m0 + q * 4 + r) * QF] = __float2half(acc[nt][r] * dv[r]);
    }
}

// ---- GEMM2 MFMA: t2q[4][M][32] = fp16( dinv[m] * (h[M,128] @ Wcat)[m] ) ----
__global__ __launch_bounds__(256) void k_gemm2_mfma(const __half* __restrict__ A,
                                                    const __half* __restrict__ Wcfrag,
                                                    const float* __restrict__ dinv,
                                                    __half* __restrict__ C, int M) {
    const int wave = threadIdx.x >> 6;
    const int lane = threadIdx.x & 63;
    const int m0 = blockIdx.x * 64 + wave * 16;
    if (m0 >= M) return;
    const int q = lane >> 4;
    const int arow = m0 + (lane & 15);
    f32x4 acc[8] = {};
#pragma unroll
    for (int ks = 0; ks < 4; ++ks) {
        f16x8 a = *(const f16x8*)(A + (size_t)ks * M * QF + (size_t)arow * QF + q * 8);
        const __half* bbase = Wcfrag + ((size_t)(ks * 8) * 64 + lane) * 8;
#pragma unroll
        for (int nt = 0; nt < 8; ++nt) {
            f16x8 bfrag = *(const f16x8*)(bbase + (size_t)nt * 64 * 8);
            acc[nt] = __builtin_amdgcn_mfma_f32_16x16x32_f16(a, bfrag, acc[nt], 0, 0, 0);
        }
    }
    float dv[4];
#pragma unroll
    for (int r = 0; r < 4; ++r) dv[r] = dinv[m0 + q * 4 + r];
#pragma unroll
    for (int nt = 0; nt < 8; ++nt) {
        int col = nt * 16 + (lane & 15);
        __half* cq = C + (size_t)(col >> 5) * M * QF + (col & 31);
#pragma unroll
        for (int r = 0; r < 4; ++r)
            cq[(size_t)(m0 + q * 4 + r) * QF] = __float2half(acc[nt][r] * dv[r]);
    }
}

// ---- issue one 32-edge chunk's staging loads (2x 16B/lane -> 2KB region) ----
#define ISSUE(C_, LB, SV)                                                      \
    {                                                                          \
        const int eidx_ = gs + (C_) * 32 + row2;                               \
        const __half* gp_ = (eidx_ < ge)                                       \
            ? (tq + (size_t)(SV) * QF + halfo) : (zrow + halfo);               \
        __builtin_amdgcn_global_load_lds(                                      \
            (const __attribute__((address_space(1))) void*)gp_,                \
            (__attribute__((address_space(3))) void*)(LB), 16, 0, 0);          \
        __builtin_amdgcn_global_load_lds(                                      \
            (const __attribute__((address_space(1))) void*)(gp_ + 16),         \
            (__attribute__((address_space(3))) void*)((LB) + 512), 16, 0, 0);  \
    }

// ---- grouped MFMA gather: wave = (16-node group, quarter), XCD-pinned ----
// blockIdx round-robins over XCDs; quarter = (bid&7)>>1 keeps each quarter's
// 3.2MB table resident in one XCD pair's L2.
template<bool FIRST>
__global__ __launch_bounds__(256) void k_gather_mfma(
        const int* __restrict__ rs, const int* __restrict__ re,
        const int* __restrict__ ssrc, const float* __restrict__ dinv,
        const __half* __restrict__ t, const __half* __restrict__ zrow,
        const float* __restrict__ bA, const float* __restrict__ bB,
        __half* __restrict__ h, float* __restrict__ out,
        int N, int NG) {
    __shared__ __align__(16) __half smem[4][2][1024];   // per wave: 2 x 2KB
    const int wave = threadIdx.x >> 6;
    const int lane = threadIdx.x & 63;
    const int x = blockIdx.x & 7;          // XCD slot (round-robin dispatch)
    const int q = x >> 1;                  // quarter pinned to XCD pair
    const int g = (((blockIdx.x >> 3) << 1) + (x & 1)) * 4 + wave;
    if (g >= NG) return;
    const int nb = g << 4;                 // first node of group
    const int row2 = lane >> 1;            // edge slot 0..31 (staging)
    const int halfo = (lane & 1) * 8;      // f16 offset of 16B half-row
    const int col = lane & 15;
    const __half* tq = t + (size_t)q * N * QF;
    __half* buf0 = &smem[wave][0][0];
    __half* buf1 = &smem[wave][1][0];
    const int o0 = rs[nb + col];           // node (=A row) col's edge range
    const int o1 = re[nb + col];
    const int gs = rs[nb];                 // group edge range (contiguous CSR)
    const int ge = re[nb + 15];
    const int nc = (ge - gs + 31) >> 5;
    const int m0 = (lane >> 4) << 2;       // A k->edge permutation base
    const int ebase = gs + m0 - o0;
    const unsigned dd = (unsigned)(o1 - o0);
    f32x4 acc0 = {}, acc1 = {};

    auto ldsrc = [&](int c) -> int {
        int idx = gs + c * 32 + row2;
        idx = idx < ge ? idx : (ge - 1);
        return __builtin_nontemporal_load(ssrc + idx);
    };

    int sv_b = 0, sv_c = 0;
    if (nc > 0) {
        const int sv_a = ldsrc(0);
        sv_b = ldsrc(1);
        sv_c = ldsrc(2);
        ISSUE(0, buf0, sv_a);
    }
    for (int c = 0; c < nc; ++c) {
        __half* cur = (c & 1) ? buf1 : buf0;
        if (c + 1 < nc) {
            __half* nxt = (c & 1) ? buf0 : buf1;
            ISSUE(c + 1, nxt, sv_b);
            int sv_n = ldsrc(c + 3);       // clamped; 2-iter latency slack
            asm volatile("s_waitcnt vmcnt(3)" ::: "memory");  // chunk c ready
            sv_b = sv_c; sv_c = sv_n;
        } else {
            asm volatile("s_waitcnt vmcnt(0)" ::: "memory");
        }
        const uint32_t va = lds_addr(cur) + 8u * lane;
        f16x4 r0, r1, r2, r3;
        asm volatile(
            "ds_read_b64_tr_b16 %0, %4 offset:0\n\t"
            "ds_read_b64_tr_b16 %1, %4 offset:512\n\t"
            "ds_read_b64_tr_b16 %2, %4 offset:1024\n\t"
            "ds_read_b64_tr_b16 %3, %4 offset:1536\n\t"
            "s_waitcnt lgkmcnt(0)"
            : "=&v"(r0), "=&v"(r1), "=&v"(r2), "=&v"(r3)
            : "v"(va) : "memory");
        __builtin_amdgcn_sched_barrier(0);
        f16x8 bf0, bf1;
#pragma unroll
        for (int j = 0; j < 4; ++j) {
            bf0[j] = r0[j]; bf0[j + 4] = r1[j];
            bf1[j] = r2[j]; bf1[j + 4] = r3[j];
        }
        // A flags: k = 8g+j maps to edge m0 + (j&3) + 16*(j>>2) within chunk
        const int eb = ebase + c * 32;
        f16x8 af;
#pragma unroll
        for (int j = 0; j < 8; ++j) {
            int m = eb + (j & 3) + ((j >> 2) << 4);
            af[j] = ((unsigned)m < dd) ? (_Float16)1.0f : (_Float16)0.0f;
        }
        acc0 = __builtin_amdgcn_mfma_f32_16x16x32_f16(af, bf0, acc0, 0, 0, 0);
        acc1 = __builtin_amdgcn_mfma_f32_16x16x32_f16(af, bf1, acc1, 0, 0, 0);
    }
    // epilogue: D row = node-in-group = (lane>>4)*4 + reg, col = lane&15
    const int nl0 = (lane >> 4) << 2;
#pragma unroll
    for (int r2 = 0; r2 < 4; ++r2) {
        const int node = nb + nl0 + r2;
        const float di = dinv[node];
        const float s0 = __half2float(tq[(size_t)node * QF + col]);
        const float s1 = __half2float(tq[(size_t)node * QF + 16 + col]);
        float v0 = (acc0[r2] + s0) * di;
        float v1 = (acc1[r2] + s1) * di;
        if constexpr (FIRST) {
            v0 += bA[q * QF + col];
            v1 += bA[q * QF + 16 + col];
            _Float16* hp = (_Float16*)(h + (size_t)q * N * QF + (size_t)node * QF);
            __builtin_nontemporal_store((_Float16)fmaxf(v0, 0.f), hp + col);
            __builtin_nontemporal_store((_Float16)fmaxf(v1, 0.f), hp + 16 + col);
        } else {
            const float* bp = (q < 2) ? bA : bB;
            const int fb = (q & 1) * QF;
            v0 += bp[fb + col];
            v1 += bp[fb + 16 + col];
            float* op = (q < 2) ? (out + (size_t)node * F2 + fb)
                                : (out + (size_t)N * F2 + (size_t)node * F2 + fb);
            __builtin_nontemporal_store(v0, op + col);
            __builtin_nontemporal_store(v1, op + 16 + col);
        }
    }
}

extern "C" void kernel_launch(void* const* d_in, const int* in_sizes, int n_in,
                              void* d_out, int out_size, void* d_ws, size_t ws_size,
                              hipStream_t stream) {
    const float* x   = (const float*)d_in[0];
    const int*   ei  = (const int*)d_in[1];
    const float* W1  = (const float*)d_in[3];
    const float* b1  = (const float*)d_in[4];
    const float* Wmu = (const float*)d_in[5];
    const float* bmu = (const float*)d_in[6];
    const float* Wls = (const float*)d_in[7];
    const float* bls = (const float*)d_in[8];

    const int N = in_sizes[0] / IN_DIM;
    const int E = in_sizes[1] / 2;
    const int* src = ei;
    const int* dst = ei + E;
    float* out = (float*)d_out;
    const int nbuck = cdiv_i(N, BN);   // 391

    // ---- workspace carve (units: 4B slots) ----
    size_t off = 0;
    auto carve = [&](size_t n) { size_t o = off; off += (n + 3) & ~(size_t)3; return o; };
    float* ws = (float*)d_ws;
    float*  dinv   =        ws + carve(N);
    int*    rs     = (int*)(ws + carve(N));
    int*    re     = (int*)(ws + carve(N));
    int*    bcur   = (int*)(ws + carve(512));
    __half* zrow   = (__half*)(ws + carve(16));   // 64B zero row
    int*    ssrc   = (int*)(ws + carve((size_t)nbuck * CAP));
    __half* t16    = (__half*)(ws + carve((size_t)N * F1 / 2));  // [4][N][32]
    __half* h16    = (__half*)(ws + carve((size_t)N * F1 / 2));  // [4][N][32]
    __half* W1frag = (__half*)(ws + carve(8 * 8 * 64 * 8 / 2));
    __half* Wcfrag = (__half*)(ws + carve(4 * 8 * 64 * 8 / 2));
    (void)ws_size;
    // pairs (nbuck*CAP ints = 7.4MB) alias t16 (12.8MB): consumed by
    // k_bucket_build before GEMM1 writes t16.
    int* pairs = (int*)t16;
    __half* t2_16 = t16;   // GEMM2 output reuses t16 (dead after gather1)

    k_prep_frags<<<cdiv_i(8 * 8 * 64 + 4 * 8 * 64, 256), 256, 0, stream>>>(
        W1, Wmu, Wls, W1frag, Wcfrag);

    // CSR build: memset (bcur + zrow, contiguous) + binning + bucket_build
    hipMemsetAsync(bcur, 0, sizeof(int) * 512 + 64, stream);
    k_binning<<<cdiv_i(E, BIN_EDGES), 512, 0, stream>>>(src, dst, bcur, pairs, E);
    k_bucket_build<<<nbuck, 512, 0, stream>>>(pairs, bcur, dinv, rs, re, ssrc, N);

    const int NG = N >> 4;              // 3125 groups of 16 (N % 16 == 0)
    const int NBI = cdiv_i(NG, 8);      // block-octets: grid divisible by 8

    // GEMM1 (MFMA): t16 = fp16(dinv * (x @ W1)), quarter-split layout
    k_gemm1_mfma<<<cdiv_i(N, 64), 256, 0, stream>>>(x, W1frag, dinv, t16, N);
    // conv1 aggregate (grouped MFMA-gather, XCD-pinned) + bias + relu -> h16
    k_gather_mfma<true><<<8 * NBI, 256, 0, stream>>>(
        rs, re, ssrc, dinv, t16, zrow, b1, b1, h16, out, N, NG);
    // GEMM2 (MFMA): t2 = fp16(dinv * (h @ Wcat)), quarter-split
    k_gemm2_mfma<<<cdiv_i(N, 64), 256, 0, stream>>>(h16, Wcfrag, dinv, t2_16, N);
    // conv2 aggregate (grouped MFMA-gather, XCD-pinned) -> out (mu||logstd)
    k_gather_mfma<false><<<8 * NBI, 256, 0, stream>>>(
        rs, re, ssrc, dinv, t2_16, zrow, bmu, bls, h16, out, N, NG);
}

// Round 8
// 246.479 us; speedup vs baseline: 1.2413x; 1.2413x over previous
//
#include <hip/hip_runtime.h>
#include <hip/hip_fp16.h>

// VGAE on GCN: N=50000, E=1.6M, IN=256, HIDDEN=128, OUT=64.
// Round 18: grouped MFMA-gather, ssrc-out-of-queue + full-line staging.
// Key fix vs R15-17 (~70us floor): vmcnt retires IN ORDER, so any per-chunk
// ssrc load (esp. HBM-cold) head-of-line-blocks every stage wait. Now the
// prologue bulk-loads the group's ssrc (<=768 ints) into per-wave LDS via
// global_load_lds; the chunk loop's VMEM queue is pure stage loads
// (L2-resident table rows) with counted vmcnt(2).
// Staging is 4 lanes/edge (full 64B row, one coalesced line request); LDS is
// edge-major [32][32] f16; tr-read per-lane addr re-derived:
// va = base + 256*(l>>4) + 64*((l>>2)&3) + 8*(l&3), offsets 0/1024/32/1056.
// A-membership flags unchanged. XCD pinning kept (quarter = (bid&7)>>1).

#define IN_DIM 256
#define F1 128   // HIDDEN
#define F2 64    // OUT
#define QF 32    // features per quarter (F1/4)
#define BN 128        // nodes per bucket
#define CAP 4736      // bucket capacity: mean 4096, +10 sigma
#define BIN_EDGES 4096  // edges per binning block (512 thr x 8)
#define SIDX 768      // per-wave LDS ssrc capacity (ints) = 24 chunks

typedef _Float16 f16x8 __attribute__((ext_vector_type(8)));
typedef _Float16 f16x4 __attribute__((ext_vector_type(4)));
typedef float f32x4 __attribute__((ext_vector_type(4)));

static inline int cdiv_i(int a, int b) { return (a + b - 1) / b; }

__device__ static inline uint32_t lds_addr(const void* p) {
    return (uint32_t)(size_t)(const __attribute__((address_space(3))) void*)p;
}

// ---- weight prep: fragment-ordered fp16 buffers ----
__global__ void k_prep_frags(const float* __restrict__ W1,
                             const float* __restrict__ Wmu,
                             const float* __restrict__ Wls,
                             __half* __restrict__ W1frag,
                             __half* __restrict__ Wcfrag) {
    int t = blockIdx.x * blockDim.x + threadIdx.x;
    if (t < 8 * 8 * 64) {
        int lane = t & 63, nt = (t >> 6) & 7, ks = t >> 9;
        int k0 = ks * 32 + ((lane >> 4) << 3);
        int n = nt * 16 + (lane & 15);
#pragma unroll
        for (int j = 0; j < 8; ++j)
            W1frag[(size_t)t * 8 + j] = __float2half(W1[(k0 + j) * F1 + n]);
    } else if (t < 8 * 8 * 64 + 4 * 8 * 64) {
        int u = t - 8 * 8 * 64;
        int lane = u & 63, nt = (u >> 6) & 7, ks = u >> 9;
        int k0 = ks * 32 + ((lane >> 4) << 3);
        int c = nt * 16 + (lane & 15);
        const float* W = (c < F2) ? (Wmu + c) : (Wls + (c - F2));
#pragma unroll
        for (int j = 0; j < 8; ++j)
            Wcfrag[(size_t)u * 8 + j] = __float2half(W[(k0 + j) * F2]);
    }
}

// ---- pass 1: bin edges by dst>>7; packed pair = (dst&127)<<16 | src ----
__global__ __launch_bounds__(512) void k_binning(const int* __restrict__ src,
                                                 const int* __restrict__ dst,
                                                 int* __restrict__ bcur,
                                                 int* __restrict__ pairs, int E) {
    __shared__ int hcnt[512];
    __shared__ int hrank[512];
    __shared__ int hbase[512];
    __shared__ int lbase[512];
    __shared__ int stage[BIN_EDGES];
    __shared__ int gaddr[BIN_EDGES];
    const int tid = threadIdx.x;
    hcnt[tid] = 0; hrank[tid] = 0;
    __syncthreads();
    const int e0 = blockIdx.x * BIN_EDGES;
    int s_[8], d_[8];
#pragma unroll
    for (int it = 0; it < 8; ++it) {
        int e = e0 + it * 512 + tid;
        if (e < E) {
            s_[it] = src[e];
            d_[it] = dst[e];
            atomicAdd(&hcnt[d_[it] >> 7], 1);
        } else {
            d_[it] = -1;
        }
    }
    __syncthreads();
    int v = hcnt[tid];
    lbase[tid] = v;
    __syncthreads();
    for (int ofs = 1; ofs < 512; ofs <<= 1) {
        int add = (tid >= ofs) ? lbase[tid - ofs] : 0;
        __syncthreads();
        lbase[tid] += add;
        __syncthreads();
    }
    int total = lbase[511];
    int excl = lbase[tid] - v;
    __syncthreads();
    lbase[tid] = excl;
    hbase[tid] = v ? atomicAdd(&bcur[tid], v) : 0;
    __syncthreads();
#pragma unroll
    for (int it = 0; it < 8; ++it) {
        if (d_[it] >= 0) {
            int b = d_[it] >> 7;
            int r = atomicAdd(&hrank[b], 1);
            int li = lbase[b] + r;
            stage[li] = ((d_[it] & (BN - 1)) << 16) | s_[it];
            gaddr[li] = b * CAP + hbase[b] + r;
        }
    }
    __syncthreads();
    for (int i = tid; i < total; i += 512)
        pairs[gaddr[i]] = stage[i];
}

// ---- pass 2: per-bucket histogram -> scan -> dinv + [rs,re) + staged ssrc ----
__global__ __launch_bounds__(512) void k_bucket_build(const int* __restrict__ pairs,
                                                      const int* __restrict__ bcur,
                                                      float* __restrict__ dinv,
                                                      int* __restrict__ rs,
                                                      int* __restrict__ re,
                                                      int* __restrict__ ssrc, int N) {
    __shared__ int hist[BN];
    __shared__ int offs[BN];
    __shared__ int stage[CAP];
    const int b = blockIdx.x;
    const int n0 = b * BN;
    const int tid = threadIdx.x;
    const int pbase = b * CAP;
    const int cnt = min(bcur[b], CAP);
    if (tid < BN) hist[tid] = 0;
    __syncthreads();
    for (int e = tid; e < cnt; e += 512)
        atomicAdd(&hist[pairs[pbase + e] >> 16], 1);
    __syncthreads();
    if (tid < BN) offs[tid] = hist[tid];
    __syncthreads();
    for (int ofs = 1; ofs < BN; ofs <<= 1) {
        int add = 0;
        if (tid < BN && tid >= ofs) add = offs[tid - ofs];
        __syncthreads();
        if (tid < BN) offs[tid] += add;
        __syncthreads();
    }
    if (tid < BN) {
        int incl = offs[tid];
        int excl = incl - hist[tid];
        int n = n0 + tid;
        if (n < N) {
            dinv[n] = rsqrtf((float)hist[tid] + 1.0f);   // +1 self-loop
            rs[n] = pbase + excl;
            re[n] = pbase + incl;
        }
        offs[tid] = excl;
    }
    __syncthreads();
    for (int e = tid; e < cnt; e += 512) {
        int p = pairs[pbase + e];
        int idx = atomicAdd(&offs[p >> 16], 1);
        stage[idx] = p & 0xFFFF;
    }
    __syncthreads();
    for (int i = tid; i < cnt; i += 512) ssrc[pbase + i] = stage[i];
}

// ---- GEMM1 MFMA: tq[4][M][32] = fp16( dinv[m] * (x[M,256] @ W1)[m] ) ----
__global__ __launch_bounds__(256) void k_gemm1_mfma(const float* __restrict__ x,
                                                    const __half* __restrict__ W1frag,
                                                    const float* __restrict__ dinv,
                                                    __half* __restrict__ C, int M) {
    const int wave = threadIdx.x >> 6;
    const int lane = threadIdx.x & 63;
    const int m0 = blockIdx.x * 64 + wave * 16;
    if (m0 >= M) return;
    const int q = lane >> 4;
    const int arow = m0 + (lane & 15);
    f32x4 acc[8] = {};
#pragma unroll
    for (int ks = 0; ks < 8; ++ks) {
        const float* ap = x + (size_t)arow * IN_DIM + ks * 32 + q * 8;
        f32x4 f0 = *(const f32x4*)(ap);
        f32x4 f1 = *(const f32x4*)(ap + 4);
        f16x8 a = { (_Float16)f0.x, (_Float16)f0.y, (_Float16)f0.z, (_Float16)f0.w,
                    (_Float16)f1.x, (_Float16)f1.y, (_Float16)f1.z, (_Float16)f1.w };
        const __half* bbase = W1frag + ((size_t)(ks * 8) * 64 + lane) * 8;
#pragma unroll
        for (int nt = 0; nt < 8; ++nt) {
            f16x8 bfrag = *(const f16x8*)(bbase + (size_t)nt * 64 * 8);
            acc[nt] = __builtin_amdgcn_mfma_f32_16x16x32_f16(a, bfrag, acc[nt], 0, 0, 0);
        }
    }
    float dv[4];
#pragma unroll
    for (int r = 0; r < 4; ++r) dv[r] = dinv[m0 + q * 4 + r];
#pragma unroll
    for (int nt = 0; nt < 8; ++nt) {
        int col = nt * 16 + (lane & 15);
        __half* cq = C + (size_t)(col >> 5) * M * QF + (col & 31);
#pragma unroll
        for (int r = 0; r < 4; ++r)
            cq[(size_t)(m0 + q * 4 + r) * QF] = __float2half(acc[nt][r] * dv[r]);
    }
}

// ---- GEMM2 MFMA: t2q[4][M][32] = fp16( dinv[m] * (h[M,128] @ Wcat)[m] ) ----
__global__ __launch_bounds__(256) void k_gemm2_mfma(const __half* __restrict__ A,
                                                    const __half* __restrict__ Wcfrag,
                                                    const float* __restrict__ dinv,
                                                    __half* __restrict__ C, int M) {
    const int wave = threadIdx.x >> 6;
    const int lane = threadIdx.x & 63;
    const int m0 = blockIdx.x * 64 + wave * 16;
    if (m0 >= M) return;
    const int q = lane >> 4;
    const int arow = m0 + (lane & 15);
    f32x4 acc[8] = {};
#pragma unroll
    for (int ks = 0; ks < 4; ++ks) {
        f16x8 a = *(const f16x8*)(A + (size_t)ks * M * QF + (size_t)arow * QF + q * 8);
        const __half* bbase = Wcfrag + ((size_t)(ks * 8) * 64 + lane) * 8;
#pragma unroll
        for (int nt = 0; nt < 8; ++nt) {
            f16x8 bfrag = *(const f16x8*)(bbase + (size_t)nt * 64 * 8);
            acc[nt] = __builtin_amdgcn_mfma_f32_16x16x32_f16(a, bfrag, acc[nt], 0, 0, 0);
        }
    }
    float dv[4];
#pragma unroll
    for (int r = 0; r < 4; ++r) dv[r] = dinv[m0 + q * 4 + r];
#pragma unroll
    for (int nt = 0; nt < 8; ++nt) {
        int col = nt * 16 + (lane & 15);
        __half* cq = C + (size_t)(col >> 5) * M * QF + (col & 31);
#pragma unroll
        for (int r = 0; r < 4; ++r)
            cq[(size_t)(m0 + q * 4 + r) * QF] = __float2half(acc[nt][r] * dv[r]);
    }
}

// ---- issue one 32-edge chunk: 4 lanes/edge, full 64B row per line request.
// inst A: edges 0-15 (lane l -> edge l>>2, bytes 16*(l&3)); dest LB (linear
// lane*16 = edge-major [16][32] f16). inst B: edges 16-31 -> LB+512 f16. ----
#define ISSUE4(C_, LB, SA, SB)                                                 \
    {                                                                          \
        const int ebA_ = gs + (C_) * 32 + e4;                                  \
        const int ebB_ = ebA_ + 16;                                            \
        const __half* gpA_ = (ebA_ < ge)                                       \
            ? (tq + (size_t)(SA) * QF + b8) : (zrow + b8);                     \
        const __half* gpB_ = (ebB_ < ge)                                       \
            ? (tq + (size_t)(SB) * QF + b8) : (zrow + b8);                     \
        __builtin_amdgcn_global_load_lds(                                      \
            (const __attribute__((address_space(1))) void*)gpA_,               \
            (__attribute__((address_space(3))) void*)(LB), 16, 0, 0);          \
        __builtin_amdgcn_global_load_lds(                                      \
            (const __attribute__((address_space(1))) void*)gpB_,               \
            (__attribute__((address_space(3))) void*)((LB) + 512), 16, 0, 0);  \
    }

// ---- grouped MFMA gather: wave = (16-node group, quarter), XCD-pinned ----
template<bool FIRST>
__global__ __launch_bounds__(256) void k_gather_mfma(
        const int* __restrict__ rs, const int* __restrict__ re,
        const int* __restrict__ ssrc, const float* __restrict__ dinv,
        const __half* __restrict__ t, const __half* __restrict__ zrow,
        const float* __restrict__ bA, const float* __restrict__ bB,
        __half* __restrict__ h, float* __restrict__ out,
        int N, int NG) {
    __shared__ __align__(16) __half smem[4][2][1024];   // stage dbuf 2x2KB/wave
    __shared__ __align__(16) int    sidx[4][SIDX];      // ssrc 3KB/wave
    const int wave = threadIdx.x >> 6;
    const int lane = threadIdx.x & 63;
    const int x = blockIdx.x & 7;          // XCD slot (round-robin dispatch)
    const int q = x >> 1;                  // quarter pinned to XCD pair
    const int g = (((blockIdx.x >> 3) << 1) + (x & 1)) * 4 + wave;
    if (g >= NG) return;
    const int nb = g << 4;                 // first node of group
    const int e4 = lane >> 2;              // edge-in-halfchunk 0..15 (staging)
    const int b8 = (lane & 3) * 8;         // f16 offset of 16B quarter-row part
    const int col = lane & 15;
    const __half* tq = t + (size_t)q * N * QF;
    __half* buf0 = &smem[wave][0][0];
    __half* buf1 = &smem[wave][1][0];
    int* sb = &sidx[wave][0];
    const int o0 = rs[nb + col];           // node (=A row) col's edge range
    const int o1 = re[nb + col];
    const int gs = rs[nb];                 // group edge range (contiguous CSR)
    const int ge = re[nb + 15];
    const int ne = ge - gs;
    const int nc = (ne + 31) >> 5;
    const int m0 = (lane >> 4) << 2;       // A k->edge permutation base
    const int ebase = gs + m0 - o0;
    const unsigned dd = (unsigned)(o1 - o0);
    // tr-read lane offset for edge-major [32][32] LDS:
    const uint32_t voff = 256u * (lane >> 4) + 64u * ((lane >> 2) & 3)
                        + 8u * (lane & 3);
    const uint32_t va0 = lds_addr(buf0) + voff;
    const uint32_t va1 = lds_addr(buf1) + voff;
    f32x4 acc0 = {}, acc1 = {};

    auto getsv = [&](int C, int& A_, int& B_) {
        int ia = C * 32 + e4;
        if (C < SIDX / 32) {               // wave-uniform
            A_ = sb[ia];
            B_ = sb[ia + 16];
        } else {                            // rare overflow: direct global
            int cap = ne > 0 ? ne - 1 : 0;
            A_ = ssrc[gs + min(ia, cap)];
            B_ = ssrc[gs + min(ia + 16, cap)];
        }
    };

    if (nc > 0) {
        // prologue: bulk ssrc -> LDS (1KB per block, 256 ints, 16B/lane)
        const int nblk = min((ne + 255) >> 8, SIDX / 256);
        for (int b = 0; b < nblk; ++b)
            __builtin_amdgcn_global_load_lds(
                (const __attribute__((address_space(1))) void*)(ssrc + gs + b * 256 + lane * 4),
                (__attribute__((address_space(3))) void*)(sb + b * 256), 16, 0, 0);
        asm volatile("s_waitcnt vmcnt(0)" ::: "memory");   // ssrc resident
        int svA, svB;
        getsv(0, svA, svB);
        ISSUE4(0, buf0, svA, svB);
        getsv(1, svA, svB);
        for (int c = 0; c < nc; ++c) {
            if (c + 1 < nc) {
                ISSUE4(c + 1, (c & 1) ? buf0 : buf1, svA, svB);
                getsv(c + 2, svA, svB);    // prefetch for next iter's ISSUE
                asm volatile("s_waitcnt vmcnt(2)" ::: "memory");  // stage(c) done
            } else {
                asm volatile("s_waitcnt vmcnt(0)" ::: "memory");
            }
            const uint32_t va = (c & 1) ? va1 : va0;
            f16x4 r0, r1, r2, r3;
            asm volatile(
                "ds_read_b64_tr_b16 %0, %4 offset:0\n\t"
                "ds_read_b64_tr_b16 %1, %4 offset:1024\n\t"
                "ds_read_b64_tr_b16 %2, %4 offset:32\n\t"
                "ds_read_b64_tr_b16 %3, %4 offset:1056\n\t"
                "s_waitcnt lgkmcnt(0)"
                : "=&v"(r0), "=&v"(r1), "=&v"(r2), "=&v"(r3)
                : "v"(va) : "memory");
            __builtin_amdgcn_sched_barrier(0);
            f16x8 bf0, bf1;
#pragma unroll
            for (int j = 0; j < 4; ++j) {
                bf0[j] = r0[j]; bf0[j + 4] = r1[j];   // feats 0-15
                bf1[j] = r2[j]; bf1[j + 4] = r3[j];   // feats 16-31
            }
            // A flags: k = 8g+j -> edge m0 + (j&3) + 16*(j>>2) within chunk
            const int eb = ebase + c * 32;
            f16x8 af;
#pragma unroll
            for (int j = 0; j < 8; ++j) {
                int m = eb + (j & 3) + ((j >> 2) << 4);
                af[j] = ((unsigned)m < dd) ? (_Float16)1.0f : (_Float16)0.0f;
            }
            acc0 = __builtin_amdgcn_mfma_f32_16x16x32_f16(af, bf0, acc0, 0, 0, 0);
            acc1 = __builtin_amdgcn_mfma_f32_16x16x32_f16(af, bf1, acc1, 0, 0, 0);
        }
    }
    // epilogue: D row = node-in-group = (lane>>4)*4 + reg, col = lane&15
    const int nl0 = (lane >> 4) << 2;
#pragma unroll
    for (int r2 = 0; r2 < 4; ++r2) {
        const int node = nb + nl0 + r2;
        const float di = dinv[node];
        const float s0 = __half2float(tq[(size_t)node * QF + col]);
        const float s1 = __half2float(tq[(size_t)node * QF + 16 + col]);
        float v0 = (acc0[r2] + s0) * di;
        float v1 = (acc1[r2] + s1) * di;
        if constexpr (FIRST) {
            v0 += bA[q * QF + col];
            v1 += bA[q * QF + 16 + col];
            _Float16* hp = (_Float16*)(h + (size_t)q * N * QF + (size_t)node * QF);
            __builtin_nontemporal_store((_Float16)fmaxf(v0, 0.f), hp + col);
            __builtin_nontemporal_store((_Float16)fmaxf(v1, 0.f), hp + 16 + col);
        } else {
            const float* bp = (q < 2) ? bA : bB;
            const int fb = (q & 1) * QF;
            v0 += bp[fb + col];
            v1 += bp[fb + 16 + col];
            float* op = (q < 2) ? (out + (size_t)node * F2 + fb)
                                : (out + (size_t)N * F2 + (size_t)node * F2 + fb);
            __builtin_nontemporal_store(v0, op + col);
            __builtin_nontemporal_store(v1, op + 16 + col);
        }
    }
}

extern "C" void kernel_launch(void* const* d_in, const int* in_sizes, int n_in,
                              void* d_out, int out_size, void* d_ws, size_t ws_size,
                              hipStream_t stream) {
    const float* x   = (const float*)d_in[0];
    const int*   ei  = (const int*)d_in[1];
    const float* W1  = (const float*)d_in[3];
    const float* b1  = (const float*)d_in[4];
    const float* Wmu = (const float*)d_in[5];
    const float* bmu = (const float*)d_in[6];
    const float* Wls = (const float*)d_in[7];
    const float* bls = (const float*)d_in[8];

    const int N = in_sizes[0] / IN_DIM;
    const int E = in_sizes[1] / 2;
    const int* src = ei;
    const int* dst = ei + E;
    float* out = (float*)d_out;
    const int nbuck = cdiv_i(N, BN);   // 391

    // ---- workspace carve (units: 4B slots) ----
    size_t off = 0;
    auto carve = [&](size_t n) { size_t o = off; off += (n + 3) & ~(size_t)3; return o; };
    float* ws = (float*)d_ws;
    float*  dinv   =        ws + carve(N);
    int*    rs     = (int*)(ws + carve(N));
    int*    re     = (int*)(ws + carve(N));
    int*    bcur   = (int*)(ws + carve(512));
    __half* zrow   = (__half*)(ws + carve(16));   // 64B zero row
    int*    ssrc   = (int*)(ws + carve((size_t)nbuck * CAP + 256));  // +tail pad
    __half* t16    = (__half*)(ws + carve((size_t)N * F1 / 2));  // [4][N][32]
    __half* h16    = (__half*)(ws + carve((size_t)N * F1 / 2));  // [4][N][32]
    __half* W1frag = (__half*)(ws + carve(8 * 8 * 64 * 8 / 2));
    __half* Wcfrag = (__half*)(ws + carve(4 * 8 * 64 * 8 / 2));
    (void)ws_size;
    // pairs (nbuck*CAP ints = 7.4MB) alias t16 (12.8MB): consumed by
    // k_bucket_build before GEMM1 writes t16.
    int* pairs = (int*)t16;
    __half* t2_16 = t16;   // GEMM2 output reuses t16 (dead after gather1)

    k_prep_frags<<<cdiv_i(8 * 8 * 64 + 4 * 8 * 64, 256), 256, 0, stream>>>(
        W1, Wmu, Wls, W1frag, Wcfrag);

    // CSR build: memset (bcur + zrow, contiguous) + binning + bucket_build
    hipMemsetAsync(bcur, 0, sizeof(int) * 512 + 64, stream);
    k_binning<<<cdiv_i(E, BIN_EDGES), 512, 0, stream>>>(src, dst, bcur, pairs, E);
    k_bucket_build<<<nbuck, 512, 0, stream>>>(pairs, bcur, dinv, rs, re, ssrc, N);

    const int NG = N >> 4;              // 3125 groups of 16 (N % 16 == 0)
    const int NBI = cdiv_i(NG, 8);      // block-octets: grid divisible by 8

    // GEMM1 (MFMA): t16 = fp16(dinv * (x @ W1)), quarter-split layout
    k_gemm1_mfma<<<cdiv_i(N, 64), 256, 0, stream>>>(x, W1frag, dinv, t16, N);
    // conv1 aggregate (grouped MFMA-gather, XCD-pinned) + bias + relu -> h16
    k_gather_mfma<true><<<8 * NBI, 256, 0, stream>>>(
        rs, re, ssrc, dinv, t16, zrow, b1, b1, h16, out, N, NG);
    // GEMM2 (MFMA): t2 = fp16(dinv * (h @ Wcat)), quarter-split
    k_gemm2_mfma<<<cdiv_i(N, 64), 256, 0, stream>>>(h16, Wcfrag, dinv, t2_16, N);
    // conv2 aggregate (grouped MFMA-gather, XCD-pinned) -> out (mu||logstd)
    k_gather_mfma<false><<<8 * NBI, 256, 0, stream>>>(
        rs, re, ssrc, dinv, t2_16, zrow, bmu, bls, h16, out, N, NG);
}

// Round 9
// 244.456 us; speedup vs baseline: 1.2516x; 1.0083x over previous
//
#include <hip/hip_runtime.h>
#include <hip/hip_fp16.h>

// VGAE on GCN: N=50000, E=1.6M, IN=256, HIDDEN=128, OUT=64.
// Round 19: depth-3 stage pipeline + u16 ssrc + LDS bank swizzle.
// - Ring of 4 stage buffers/wave; issue chunk c+3 then vmcnt(6) (3 chunks in
//   flight, never drained mid-loop); tail 4->2->0. Covers L2 latency.
// - ssrc stored u16 (node ids < 65536): halves CSR+prologue traffic; sidx LDS
//   2KB/wave -> total 40KB -> 4 blocks/CU.
// - Stage-buffer swizzle LDS[d]=orig[d^((d>>2)&0x20)]: global source quad
//   pre-swizzled (b8 ^= ((l>>3)&1)<<4), tr-read addr vaLo = base+(voff^((u&2)<<4)),
//   vaHi = vaLo^32. Group banks -> 16(u&1)+8(u>>1)+2v: conflict-free.
// Kept: grouped MFMA-gather (A=membership flags), XCD-pinned quarters,
// tr-read linear semantics (R15-verified), NT outputs.

#define IN_DIM 256
#define F1 128   // HIDDEN
#define F2 64    // OUT
#define QF 32    // features per quarter (F1/4)
#define BN 128        // nodes per bucket
#define CAP 4736      // bucket capacity: mean 4096, +10 sigma
#define BIN_EDGES 4096  // edges per binning block (512 thr x 8)
#define SIDW 1024     // per-wave LDS ssrc capacity (u16)
#define SBLK 512      // u16 per prologue bulk-load block

typedef _Float16 f16x8 __attribute__((ext_vector_type(8)));
typedef _Float16 f16x4 __attribute__((ext_vector_type(4)));
typedef float f32x4 __attribute__((ext_vector_type(4)));

static inline int cdiv_i(int a, int b) { return (a + b - 1) / b; }

__device__ static inline uint32_t lds_addr(const void* p) {
    return (uint32_t)(size_t)(const __attribute__((address_space(3))) void*)p;
}

// ---- weight prep: fragment-ordered fp16 buffers ----
__global__ void k_prep_frags(const float* __restrict__ W1,
                             const float* __restrict__ Wmu,
                             const float* __restrict__ Wls,
                             __half* __restrict__ W1frag,
                             __half* __restrict__ Wcfrag) {
    int t = blockIdx.x * blockDim.x + threadIdx.x;
    if (t < 8 * 8 * 64) {
        int lane = t & 63, nt = (t >> 6) & 7, ks = t >> 9;
        int k0 = ks * 32 + ((lane >> 4) << 3);
        int n = nt * 16 + (lane & 15);
#pragma unroll
        for (int j = 0; j < 8; ++j)
            W1frag[(size_t)t * 8 + j] = __float2half(W1[(k0 + j) * F1 + n]);
    } else if (t < 8 * 8 * 64 + 4 * 8 * 64) {
        int u = t - 8 * 8 * 64;
        int lane = u & 63, nt = (u >> 6) & 7, ks = u >> 9;
        int k0 = ks * 32 + ((lane >> 4) << 3);
        int c = nt * 16 + (lane & 15);
        const float* W = (c < F2) ? (Wmu + c) : (Wls + (c - F2));
#pragma unroll
        for (int j = 0; j < 8; ++j)
            Wcfrag[(size_t)u * 8 + j] = __float2half(W[(k0 + j) * F2]);
    }
}

// ---- pass 1: bin edges by dst>>7; packed pair = (dst&127)<<16 | src ----
__global__ __launch_bounds__(512) void k_binning(const int* __restrict__ src,
                                                 const int* __restrict__ dst,
                                                 int* __restrict__ bcur,
                                                 int* __restrict__ pairs, int E) {
    __shared__ int hcnt[512];
    __shared__ int hrank[512];
    __shared__ int hbase[512];
    __shared__ int lbase[512];
    __shared__ int stage[BIN_EDGES];
    __shared__ int gaddr[BIN_EDGES];
    const int tid = threadIdx.x;
    hcnt[tid] = 0; hrank[tid] = 0;
    __syncthreads();
    const int e0 = blockIdx.x * BIN_EDGES;
    int s_[8], d_[8];
#pragma unroll
    for (int it = 0; it < 8; ++it) {
        int e = e0 + it * 512 + tid;
        if (e < E) {
            s_[it] = src[e];
            d_[it] = dst[e];
            atomicAdd(&hcnt[d_[it] >> 7], 1);
        } else {
            d_[it] = -1;
        }
    }
    __syncthreads();
    int v = hcnt[tid];
    lbase[tid] = v;
    __syncthreads();
    for (int ofs = 1; ofs < 512; ofs <<= 1) {
        int add = (tid >= ofs) ? lbase[tid - ofs] : 0;
        __syncthreads();
        lbase[tid] += add;
        __syncthreads();
    }
    int total = lbase[511];
    int excl = lbase[tid] - v;
    __syncthreads();
    lbase[tid] = excl;
    hbase[tid] = v ? atomicAdd(&bcur[tid], v) : 0;
    __syncthreads();
#pragma unroll
    for (int it = 0; it < 8; ++it) {
        if (d_[it] >= 0) {
            int b = d_[it] >> 7;
            int r = atomicAdd(&hrank[b], 1);
            int li = lbase[b] + r;
            stage[li] = ((d_[it] & (BN - 1)) << 16) | s_[it];
            gaddr[li] = b * CAP + hbase[b] + r;
        }
    }
    __syncthreads();
    for (int i = tid; i < total; i += 512)
        pairs[gaddr[i]] = stage[i];
}

// ---- pass 2: per-bucket histogram -> scan -> dinv + [rs,re) + u16 ssrc ----
__global__ __launch_bounds__(512) void k_bucket_build(const int* __restrict__ pairs,
                                                      const int* __restrict__ bcur,
                                                      float* __restrict__ dinv,
                                                      int* __restrict__ rs,
                                                      int* __restrict__ re,
                                                      ushort* __restrict__ ssrc, int N) {
    __shared__ int hist[BN];
    __shared__ int offs[BN];
    __shared__ int stage[CAP];
    const int b = blockIdx.x;
    const int n0 = b * BN;
    const int tid = threadIdx.x;
    const int pbase = b * CAP;
    const int cnt = min(bcur[b], CAP);
    if (tid < BN) hist[tid] = 0;
    __syncthreads();
    for (int e = tid; e < cnt; e += 512)
        atomicAdd(&hist[pairs[pbase + e] >> 16], 1);
    __syncthreads();
    if (tid < BN) offs[tid] = hist[tid];
    __syncthreads();
    for (int ofs = 1; ofs < BN; ofs <<= 1) {
        int add = 0;
        if (tid < BN && tid >= ofs) add = offs[tid - ofs];
        __syncthreads();
        if (tid < BN) offs[tid] += add;
        __syncthreads();
    }
    if (tid < BN) {
        int incl = offs[tid];
        int excl = incl - hist[tid];
        int n = n0 + tid;
        if (n < N) {
            dinv[n] = rsqrtf((float)hist[tid] + 1.0f);   // +1 self-loop
            rs[n] = pbase + excl;
            re[n] = pbase + incl;
        }
        offs[tid] = excl;
    }
    __syncthreads();
    for (int e = tid; e < cnt; e += 512) {
        int p = pairs[pbase + e];
        int idx = atomicAdd(&offs[p >> 16], 1);
        stage[idx] = p & 0xFFFF;
    }
    __syncthreads();
    for (int i = tid; i < cnt; i += 512)
        ssrc[pbase + i] = (ushort)stage[i];
}

// ---- GEMM1 MFMA: tq[4][M][32] = fp16( dinv[m] * (x[M,256] @ W1)[m] ) ----
__global__ __launch_bounds__(256) void k_gemm1_mfma(const float* __restrict__ x,
                                                    const __half* __restrict__ W1frag,
                                                    const float* __restrict__ dinv,
                                                    __half* __restrict__ C, int M) {
    const int wave = threadIdx.x >> 6;
    const int lane = threadIdx.x & 63;
    const int m0 = blockIdx.x * 64 + wave * 16;
    if (m0 >= M) return;
    const int q = lane >> 4;
    const int arow = m0 + (lane & 15);
    f32x4 acc[8] = {};
#pragma unroll
    for (int ks = 0; ks < 8; ++ks) {
        const float* ap = x + (size_t)arow * IN_DIM + ks * 32 + q * 8;
        f32x4 f0 = *(const f32x4*)(ap);
        f32x4 f1 = *(const f32x4*)(ap + 4);
        f16x8 a = { (_Float16)f0.x, (_Float16)f0.y, (_Float16)f0.z, (_Float16)f0.w,
                    (_Float16)f1.x, (_Float16)f1.y, (_Float16)f1.z, (_Float16)f1.w };
        const __half* bbase = W1frag + ((size_t)(ks * 8) * 64 + lane) * 8;
#pragma unroll
        for (int nt = 0; nt < 8; ++nt) {
            f16x8 bfrag = *(const f16x8*)(bbase + (size_t)nt * 64 * 8);
            acc[nt] = __builtin_amdgcn_mfma_f32_16x16x32_f16(a, bfrag, acc[nt], 0, 0, 0);
        }
    }
    float dv[4];
#pragma unroll
    for (int r = 0; r < 4; ++r) dv[r] = dinv[m0 + q * 4 + r];
#pragma unroll
    for (int nt = 0; nt < 8; ++nt) {
        int col = nt * 16 + (lane & 15);
        __half* cq = C + (size_t)(col >> 5) * M * QF + (col & 31);
#pragma unroll
        for (int r = 0; r < 4; ++r)
            cq[(size_t)(m0 + q * 4 + r) * QF] = __float2half(acc[nt][r] * dv[r]);
    }
}

// ---- GEMM2 MFMA: t2q[4][M][32] = fp16( dinv[m] * (h[M,128] @ Wcat)[m] ) ----
__global__ __launch_bounds__(256) void k_gemm2_mfma(const __half* __restrict__ A,
                                                    const __half* __restrict__ Wcfrag,
                                                    const float* __restrict__ dinv,
                                                    __half* __restrict__ C, int M) {
    const int wave = threadIdx.x >> 6;
    const int lane = threadIdx.x & 63;
    const int m0 = blockIdx.x * 64 + wave * 16;
    if (m0 >= M) return;
    const int q = lane >> 4;
    const int arow = m0 + (lane & 15);
    f32x4 acc[8] = {};
#pragma unroll
    for (int ks = 0; ks < 4; ++ks) {
        f16x8 a = *(const f16x8*)(A + (size_t)ks * M * QF + (size_t)arow * QF + q * 8);
        const __half* bbase = Wcfrag + ((size_t)(ks * 8) * 64 + lane) * 8;
#pragma unroll
        for (int nt = 0; nt < 8; ++nt) {
            f16x8 bfrag = *(const f16x8*)(bbase + (size_t)nt * 64 * 8);
            acc[nt] = __builtin_amdgcn_mfma_f32_16x16x32_f16(a, bfrag, acc[nt], 0, 0, 0);
        }
    }
    float dv[4];
#pragma unroll
    for (int r = 0; r < 4; ++r) dv[r] = dinv[m0 + q * 4 + r];
#pragma unroll
    for (int nt = 0; nt < 8; ++nt) {
        int col = nt * 16 + (lane & 15);
        __half* cq = C + (size_t)(col >> 5) * M * QF + (col & 31);
#pragma unroll
        for (int r = 0; r < 4; ++r)
            cq[(size_t)(m0 + q * 4 + r) * QF] = __float2half(acc[nt][r] * dv[r]);
    }
}

// ---- issue one 32-edge chunk: 4 lanes/edge, full 64B row per line request.
// Source quad pre-swizzled (b8s) so linear LDS dest realizes the bank swizzle.
#define ISSUE4(C_, LB, SA, SB)                                                 \
    {                                                                          \
        const int ebA_ = gs + (C_) * 32 + e4;                                  \
        const int ebB_ = ebA_ + 16;                                            \
        const __half* gpA_ = (ebA_ < ge)                                       \
            ? (tq + (size_t)(SA) * QF + b8s) : (zrow + b8s);                   \
        const __half* gpB_ = (ebB_ < ge)                                       \
            ? (tq + (size_t)(SB) * QF + b8s) : (zrow + b8s);                   \
        __builtin_amdgcn_global_load_lds(                                      \
            (const __attribute__((address_space(1))) void*)gpA_,               \
            (__attribute__((address_space(3))) void*)(LB), 16, 0, 0);          \
        __builtin_amdgcn_global_load_lds(                                      \
            (const __attribute__((address_space(1))) void*)gpB_,               \
            (__attribute__((address_space(3))) void*)((LB) + 512), 16, 0, 0);  \
    }

// ---- grouped MFMA gather: wave = (16-node group, quarter), XCD-pinned ----
template<bool FIRST>
__global__ __launch_bounds__(256) void k_gather_mfma(
        const int* __restrict__ rs, const int* __restrict__ re,
        const ushort* __restrict__ ssrc, const float* __restrict__ dinv,
        const __half* __restrict__ t, const __half* __restrict__ zrow,
        const float* __restrict__ bA, const float* __restrict__ bB,
        __half* __restrict__ h, float* __restrict__ out,
        int N, int NG) {
    __shared__ __align__(16) __half  smem[4][4][1024];  // stage ring 4x2KB/wave
    __shared__ __align__(16) ushort  sidx[4][SIDW];     // ssrc 2KB/wave
    const int wave = threadIdx.x >> 6;
    const int lane = threadIdx.x & 63;
    const int x = blockIdx.x & 7;          // XCD slot (round-robin dispatch)
    const int q = x >> 1;                  // quarter pinned to XCD pair
    const int g = (((blockIdx.x >> 3) << 1) + (x & 1)) * 4 + wave;
    if (g >= NG) return;
    const int nb = g << 4;                 // first node of group
    const int e4 = lane >> 2;              // edge-in-halfchunk 0..15 (staging)
    // swizzled source quad: b8s = 8*(l&3) XOR 16*((l>>3)&1)  (halfs)
    const int b8s = (8 * (lane & 3)) ^ (((lane >> 3) & 1) << 4);
    const int col = lane & 15;
    const __half* tq = t + (size_t)q * N * QF;
    __half* stg = &smem[wave][0][0];
    ushort* sb = &sidx[wave][0];
    const int o0 = rs[nb + col];           // node (=A row) col's edge range
    const int o1 = re[nb + col];
    const int gs = rs[nb];                 // group edge range (contiguous CSR)
    const int ge = re[nb + 15];
    const int ne = ge - gs;
    const int nc = (ne + 31) >> 5;
    const int m0 = (lane >> 4) << 2;       // A k->edge permutation base
    const int ebase = gs + m0 - o0;
    const unsigned dd = (unsigned)(o1 - o0);
    // tr-read addr (edge-major [32][32] + bank swizzle):
    const int u_ = (lane >> 2) & 3;
    const uint32_t voff = 256u * (uint32_t)(lane >> 4) + 64u * (uint32_t)u_
                        + 8u * (uint32_t)(lane & 3);
    const uint32_t vaL = lds_addr(stg) + (voff ^ (uint32_t)((u_ & 2) << 4));
    f32x4 acc0 = {}, acc1 = {};

    const int gsa = gs & ~7;               // 16B-aligned prologue start (u16)
    const int ofs = gs - gsa;

    auto getsv = [&](int C, int& A_, int& B_) {
        int ia = C * 32 + e4;
        if (ofs + C * 32 + 32 <= SIDW) {   // wave-uniform condition
            A_ = sb[ofs + ia];
            B_ = sb[ofs + ia + 16];
        } else {                            // rare overflow: direct global
            int cap = ne > 0 ? ne - 1 : 0;
            A_ = ssrc[gs + min(ia, cap)];
            B_ = ssrc[gs + min(ia + 16, cap)];
        }
    };

    if (nc > 0) {
        // prologue: bulk ssrc -> LDS (512 u16 = 1KB per block instr)
        const int nblk = min((ofs + ne + SBLK - 1) / SBLK, SIDW / SBLK);
        for (int b = 0; b < nblk; ++b)
            __builtin_amdgcn_global_load_lds(
                (const __attribute__((address_space(1))) void*)(ssrc + gsa + b * SBLK + lane * 8),
                (__attribute__((address_space(3))) void*)(sb + b * SBLK), 16, 0, 0);
        asm volatile("s_waitcnt vmcnt(0)" ::: "memory");   // ssrc resident
        int svA, svB;
        const int pre = min(nc, 3);
        for (int p = 0; p < pre; ++p) {    // issue chunks 0..2
            getsv(p, svA, svB);
            ISSUE4(p, stg + (p << 10), svA, svB);
        }
        getsv(3, svA, svB);
        for (int c = 0; c < nc; ++c) {
            const int jn = c + 3;
            if (jn < nc) {
                ISSUE4(jn, stg + ((jn & 3) << 10), svA, svB);
                getsv(jn + 1, svA, svB);   // prefetch for next iter's ISSUE
                asm volatile("s_waitcnt vmcnt(6)" ::: "memory");  // chunk c done
            } else {
                const int rem = nc - 1 - c;
                if (rem >= 2)      asm volatile("s_waitcnt vmcnt(4)" ::: "memory");
                else if (rem == 1) asm volatile("s_waitcnt vmcnt(2)" ::: "memory");
                else               asm volatile("s_waitcnt vmcnt(0)" ::: "memory");
            }
            const uint32_t vaLc = vaL + ((uint32_t)(c & 3) << 11);
            const uint32_t vaHc = vaLc ^ 32u;
            f16x4 r0, r1, r2, r3;
            asm volatile(
                "ds_read_b64_tr_b16 %0, %4 offset:0\n\t"
                "ds_read_b64_tr_b16 %1, %4 offset:1024\n\t"
                "ds_read_b64_tr_b16 %2, %5 offset:0\n\t"
                "ds_read_b64_tr_b16 %3, %5 offset:1024\n\t"
                "s_waitcnt lgkmcnt(0)"
                : "=&v"(r0), "=&v"(r1), "=&v"(r2), "=&v"(r3)
                : "v"(vaLc), "v"(vaHc) : "memory");
            __builtin_amdgcn_sched_barrier(0);
            f16x8 bf0, bf1;
#pragma unroll
            for (int j = 0; j < 4; ++j) {
                bf0[j] = r0[j]; bf0[j + 4] = r1[j];   // feats 0-15
                bf1[j] = r2[j]; bf1[j + 4] = r3[j];   // feats 16-31
            }
            // A flags: k = 8g+j -> edge m0 + (j&3) + 16*(j>>2) within chunk
            const int eb = ebase + c * 32;
            f16x8 af;
#pragma unroll
            for (int j = 0; j < 8; ++j) {
                int m = eb + (j & 3) + ((j >> 2) << 4);
                af[j] = ((unsigned)m < dd) ? (_Float16)1.0f : (_Float16)0.0f;
            }
            acc0 = __builtin_amdgcn_mfma_f32_16x16x32_f16(af, bf0, acc0, 0, 0, 0);
            acc1 = __builtin_amdgcn_mfma_f32_16x16x32_f16(af, bf1, acc1, 0, 0, 0);
        }
    }
    // epilogue: D row = node-in-group = (lane>>4)*4 + reg, col = lane&15
    const int nl0 = (lane >> 4) << 2;
#pragma unroll
    for (int r2 = 0; r2 < 4; ++r2) {
        const int node = nb + nl0 + r2;
        const float di = dinv[node];
        const float s0 = __half2float(tq[(size_t)node * QF + col]);
        const float s1 = __half2float(tq[(size_t)node * QF + 16 + col]);
        float v0 = (acc0[r2] + s0) * di;
        float v1 = (acc1[r2] + s1) * di;
        if constexpr (FIRST) {
            v0 += bA[q * QF + col];
            v1 += bA[q * QF + 16 + col];
            _Float16* hp = (_Float16*)(h + (size_t)q * N * QF + (size_t)node * QF);
            __builtin_nontemporal_store((_Float16)fmaxf(v0, 0.f), hp + col);
            __builtin_nontemporal_store((_Float16)fmaxf(v1, 0.f), hp + 16 + col);
        } else {
            const float* bp = (q < 2) ? bA : bB;
            const int fb = (q & 1) * QF;
            v0 += bp[fb + col];
            v1 += bp[fb + 16 + col];
            float* op = (q < 2) ? (out + (size_t)node * F2 + fb)
                                : (out + (size_t)N * F2 + (size_t)node * F2 + fb);
            __builtin_nontemporal_store(v0, op + col);
            __builtin_nontemporal_store(v1, op + 16 + col);
        }
    }
}

extern "C" void kernel_launch(void* const* d_in, const int* in_sizes, int n_in,
                              void* d_out, int out_size, void* d_ws, size_t ws_size,
                              hipStream_t stream) {
    const float* x   = (const float*)d_in[0];
    const int*   ei  = (const int*)d_in[1];
    const float* W1  = (const float*)d_in[3];
    const float* b1  = (const float*)d_in[4];
    const float* Wmu = (const float*)d_in[5];
    const float* bmu = (const float*)d_in[6];
    const float* Wls = (const float*)d_in[7];
    const float* bls = (const float*)d_in[8];

    const int N = in_sizes[0] / IN_DIM;
    const int E = in_sizes[1] / 2;
    const int* src = ei;
    const int* dst = ei + E;
    float* out = (float*)d_out;
    const int nbuck = cdiv_i(N, BN);   // 391

    // ---- workspace carve (units: 4B slots) ----
    size_t off = 0;
    auto carve = [&](size_t n) { size_t o = off; off += (n + 3) & ~(size_t)3; return o; };
    float* ws = (float*)d_ws;
    float*  dinv   =        ws + carve(N);
    int*    rs     = (int*)(ws + carve(N));
    int*    re     = (int*)(ws + carve(N));
    int*    bcur   = (int*)(ws + carve(512));
    __half* zrow   = (__half*)(ws + carve(16));   // 64B zero row
    ushort* ssrc   = (ushort*)(ws + carve(((size_t)nbuck * CAP + 1024) / 2));
    __half* t16    = (__half*)(ws + carve((size_t)N * F1 / 2));  // [4][N][32]
    __half* h16    = (__half*)(ws + carve((size_t)N * F1 / 2));  // [4][N][32]
    __half* W1frag = (__half*)(ws + carve(8 * 8 * 64 * 8 / 2));
    __half* Wcfrag = (__half*)(ws + carve(4 * 8 * 64 * 8 / 2));
    (void)ws_size;
    // pairs (nbuck*CAP ints = 7.4MB) alias t16 (12.8MB): consumed by
    // k_bucket_build before GEMM1 writes t16.
    int* pairs = (int*)t16;
    __half* t2_16 = t16;   // GEMM2 output reuses t16 (dead after gather1)

    k_prep_frags<<<cdiv_i(8 * 8 * 64 + 4 * 8 * 64, 256), 256, 0, stream>>>(
        W1, Wmu, Wls, W1frag, Wcfrag);

    // CSR build: memset (bcur + zrow, contiguous) + binning + bucket_build
    hipMemsetAsync(bcur, 0, sizeof(int) * 512 + 64, stream);
    k_binning<<<cdiv_i(E, BIN_EDGES), 512, 0, stream>>>(src, dst, bcur, pairs, E);
    k_bucket_build<<<nbuck, 512, 0, stream>>>(pairs, bcur, dinv, rs, re, ssrc, N);

    const int NG = N >> 4;              // 3125 groups of 16 (N % 16 == 0)
    const int NBI = cdiv_i(NG, 8);      // block-octets: grid divisible by 8

    // GEMM1 (MFMA): t16 = fp16(dinv * (x @ W1)), quarter-split layout
    k_gemm1_mfma<<<cdiv_i(N, 64), 256, 0, stream>>>(x, W1frag, dinv, t16, N);
    // conv1 aggregate (grouped MFMA-gather, XCD-pinned) + bias + relu -> h16
    k_gather_mfma<true><<<8 * NBI, 256, 0, stream>>>(
        rs, re, ssrc, dinv, t16, zrow, b1, b1, h16, out, N, NG);
    // GEMM2 (MFMA): t2 = fp16(dinv * (h @ Wcat)), quarter-split
    k_gemm2_mfma<<<cdiv_i(N, 64), 256, 0, stream>>>(h16, Wcfrag, dinv, t2_16, N);
    // conv2 aggregate (grouped MFMA-gather, XCD-pinned) -> out (mu||logstd)
    k_gather_mfma<false><<<8 * NBI, 256, 0, stream>>>(
        rs, re, ssrc, dinv, t2_16, zrow, bmu, bls, h16, out, N, NG);
}

// Round 10
// 239.560 us; speedup vs baseline: 1.2771x; 1.0204x over previous
//
#include <hip/hip_runtime.h>
#include <hip/hip_fp16.h>

// VGAE on GCN: N=50000, E=1.6M, IN=256, HIDDEN=128, OUT=64.
// Round 20: fully software-pipelined MFMA-gather.
// - tr-reads for chunk c+1 issued at iter c, drained by COUNT (lgkmcnt(6))
//   never by stall; sv index reads folded into the same asm block
//   (ds_read_u16 x2) so all lgkm counts are exact and the compiler emits no
//   DS waits of its own inside the loop. sched_barrier(0) after each wait.
// - Uniform always-issue stage pipeline (depth 3, ring 4, vmcnt(4) fixed):
//   prefetches past nc are excluded by the A-membership flags (m>=dd for all
//   nodes when edge >= ge), so the zrow select is deleted.
// - Swizzle dropped (R19: conflict count identical -> tr-read banks are HW-
//   fixed, m217). Linear [32][32] layout, R18-verified addressing.
// Kept: 16-node groups, A=membership MFMA, XCD-pinned quarters, u16 ssrc.

#define IN_DIM 256
#define F1 128   // HIDDEN
#define F2 64    // OUT
#define QF 32    // features per quarter (F1/4)
#define BN 128        // nodes per bucket
#define CAP 4736      // bucket capacity: mean 4096, +10 sigma
#define BIN_EDGES 4096  // edges per binning block (512 thr x 8)
#define SIDW 1024     // per-wave LDS ssrc capacity (u16)
#define SBLK 512      // u16 per prologue bulk-load block

typedef _Float16 f16x8 __attribute__((ext_vector_type(8)));
typedef _Float16 f16x4 __attribute__((ext_vector_type(4)));
typedef float f32x4 __attribute__((ext_vector_type(4)));

static inline int cdiv_i(int a, int b) { return (a + b - 1) / b; }

__device__ static inline uint32_t lds_addr(const void* p) {
    return (uint32_t)(size_t)(const __attribute__((address_space(3))) void*)p;
}

// ---- weight prep: fragment-ordered fp16 buffers ----
__global__ void k_prep_frags(const float* __restrict__ W1,
                             const float* __restrict__ Wmu,
                             const float* __restrict__ Wls,
                             __half* __restrict__ W1frag,
                             __half* __restrict__ Wcfrag) {
    int t = blockIdx.x * blockDim.x + threadIdx.x;
    if (t < 8 * 8 * 64) {
        int lane = t & 63, nt = (t >> 6) & 7, ks = t >> 9;
        int k0 = ks * 32 + ((lane >> 4) << 3);
        int n = nt * 16 + (lane & 15);
#pragma unroll
        for (int j = 0; j < 8; ++j)
            W1frag[(size_t)t * 8 + j] = __float2half(W1[(k0 + j) * F1 + n]);
    } else if (t < 8 * 8 * 64 + 4 * 8 * 64) {
        int u = t - 8 * 8 * 64;
        int lane = u & 63, nt = (u >> 6) & 7, ks = u >> 9;
        int k0 = ks * 32 + ((lane >> 4) << 3);
        int c = nt * 16 + (lane & 15);
        const float* W = (c < F2) ? (Wmu + c) : (Wls + (c - F2));
#pragma unroll
        for (int j = 0; j < 8; ++j)
            Wcfrag[(size_t)u * 8 + j] = __float2half(W[(k0 + j) * F2]);
    }
}

// ---- pass 1: bin edges by dst>>7; packed pair = (dst&127)<<16 | src ----
__global__ __launch_bounds__(512) void k_binning(const int* __restrict__ src,
                                                 const int* __restrict__ dst,
                                                 int* __restrict__ bcur,
                                                 int* __restrict__ pairs, int E) {
    __shared__ int hcnt[512];
    __shared__ int hrank[512];
    __shared__ int hbase[512];
    __shared__ int lbase[512];
    __shared__ int stage[BIN_EDGES];
    __shared__ int gaddr[BIN_EDGES];
    const int tid = threadIdx.x;
    hcnt[tid] = 0; hrank[tid] = 0;
    __syncthreads();
    const int e0 = blockIdx.x * BIN_EDGES;
    int s_[8], d_[8];
#pragma unroll
    for (int it = 0; it < 8; ++it) {
        int e = e0 + it * 512 + tid;
        if (e < E) {
            s_[it] = src[e];
            d_[it] = dst[e];
            atomicAdd(&hcnt[d_[it] >> 7], 1);
        } else {
            d_[it] = -1;
        }
    }
    __syncthreads();
    int v = hcnt[tid];
    lbase[tid] = v;
    __syncthreads();
    for (int ofs = 1; ofs < 512; ofs <<= 1) {
        int add = (tid >= ofs) ? lbase[tid - ofs] : 0;
        __syncthreads();
        lbase[tid] += add;
        __syncthreads();
    }
    int total = lbase[511];
    int excl = lbase[tid] - v;
    __syncthreads();
    lbase[tid] = excl;
    hbase[tid] = v ? atomicAdd(&bcur[tid], v) : 0;
    __syncthreads();
#pragma unroll
    for (int it = 0; it < 8; ++it) {
        if (d_[it] >= 0) {
            int b = d_[it] >> 7;
            int r = atomicAdd(&hrank[b], 1);
            int li = lbase[b] + r;
            stage[li] = ((d_[it] & (BN - 1)) << 16) | s_[it];
            gaddr[li] = b * CAP + hbase[b] + r;
        }
    }
    __syncthreads();
    for (int i = tid; i < total; i += 512)
        pairs[gaddr[i]] = stage[i];
}

// ---- pass 2: per-bucket histogram -> scan -> dinv + [rs,re) + u16 ssrc ----
__global__ __launch_bounds__(512) void k_bucket_build(const int* __restrict__ pairs,
                                                      const int* __restrict__ bcur,
                                                      float* __restrict__ dinv,
                                                      int* __restrict__ rs,
                                                      int* __restrict__ re,
                                                      ushort* __restrict__ ssrc, int N) {
    __shared__ int hist[BN];
    __shared__ int offs[BN];
    __shared__ int stage[CAP];
    const int b = blockIdx.x;
    const int n0 = b * BN;
    const int tid = threadIdx.x;
    const int pbase = b * CAP;
    const int cnt = min(bcur[b], CAP);
    if (tid < BN) hist[tid] = 0;
    __syncthreads();
    for (int e = tid; e < cnt; e += 512)
        atomicAdd(&hist[pairs[pbase + e] >> 16], 1);
    __syncthreads();
    if (tid < BN) offs[tid] = hist[tid];
    __syncthreads();
    for (int ofs = 1; ofs < BN; ofs <<= 1) {
        int add = 0;
        if (tid < BN && tid >= ofs) add = offs[tid - ofs];
        __syncthreads();
        if (tid < BN) offs[tid] += add;
        __syncthreads();
    }
    if (tid < BN) {
        int incl = offs[tid];
        int excl = incl - hist[tid];
        int n = n0 + tid;
        if (n < N) {
            dinv[n] = rsqrtf((float)hist[tid] + 1.0f);   // +1 self-loop
            rs[n] = pbase + excl;
            re[n] = pbase + incl;
        }
        offs[tid] = excl;
    }
    __syncthreads();
    for (int e = tid; e < cnt; e += 512) {
        int p = pairs[pbase + e];
        int idx = atomicAdd(&offs[p >> 16], 1);
        stage[idx] = p & 0xFFFF;
    }
    __syncthreads();
    for (int i = tid; i < cnt; i += 512)
        ssrc[pbase + i] = (ushort)stage[i];
}

// ---- GEMM1 MFMA: tq[4][M][32] = fp16( dinv[m] * (x[M,256] @ W1)[m] ) ----
__global__ __launch_bounds__(256) void k_gemm1_mfma(const float* __restrict__ x,
                                                    const __half* __restrict__ W1frag,
                                                    const float* __restrict__ dinv,
                                                    __half* __restrict__ C, int M) {
    const int wave = threadIdx.x >> 6;
    const int lane = threadIdx.x & 63;
    const int m0 = blockIdx.x * 64 + wave * 16;
    if (m0 >= M) return;
    const int q = lane >> 4;
    const int arow = m0 + (lane & 15);
    f32x4 acc[8] = {};
#pragma unroll
    for (int ks = 0; ks < 8; ++ks) {
        const float* ap = x + (size_t)arow * IN_DIM + ks * 32 + q * 8;
        f32x4 f0 = *(const f32x4*)(ap);
        f32x4 f1 = *(const f32x4*)(ap + 4);
        f16x8 a = { (_Float16)f0.x, (_Float16)f0.y, (_Float16)f0.z, (_Float16)f0.w,
                    (_Float16)f1.x, (_Float16)f1.y, (_Float16)f1.z, (_Float16)f1.w };
        const __half* bbase = W1frag + ((size_t)(ks * 8) * 64 + lane) * 8;
#pragma unroll
        for (int nt = 0; nt < 8; ++nt) {
            f16x8 bfrag = *(const f16x8*)(bbase + (size_t)nt * 64 * 8);
            acc[nt] = __builtin_amdgcn_mfma_f32_16x16x32_f16(a, bfrag, acc[nt], 0, 0, 0);
        }
    }
    float dv[4];
#pragma unroll
    for (int r = 0; r < 4; ++r) dv[r] = dinv[m0 + q * 4 + r];
#pragma unroll
    for (int nt = 0; nt < 8; ++nt) {
        int col = nt * 16 + (lane & 15);
        __half* cq = C + (size_t)(col >> 5) * M * QF + (col & 31);
#pragma unroll
        for (int r = 0; r < 4; ++r)
            cq[(size_t)(m0 + q * 4 + r) * QF] = __float2half(acc[nt][r] * dv[r]);
    }
}

// ---- GEMM2 MFMA: t2q[4][M][32] = fp16( dinv[m] * (h[M,128] @ Wcat)[m] ) ----
__global__ __launch_bounds__(256) void k_gemm2_mfma(const __half* __restrict__ A,
                                                    const __half* __restrict__ Wcfrag,
                                                    const float* __restrict__ dinv,
                                                    __half* __restrict__ C, int M) {
    const int wave = threadIdx.x >> 6;
    const int lane = threadIdx.x & 63;
    const int m0 = blockIdx.x * 64 + wave * 16;
    if (m0 >= M) return;
    const int q = lane >> 4;
    const int arow = m0 + (lane & 15);
    f32x4 acc[8] = {};
#pragma unroll
    for (int ks = 0; ks < 4; ++ks) {
        f16x8 a = *(const f16x8*)(A + (size_t)ks * M * QF + (size_t)arow * QF + q * 8);
        const __half* bbase = Wcfrag + ((size_t)(ks * 8) * 64 + lane) * 8;
#pragma unroll
        for (int nt = 0; nt < 8; ++nt) {
            f16x8 bfrag = *(const f16x8*)(bbase + (size_t)nt * 64 * 8);
            acc[nt] = __builtin_amdgcn_mfma_f32_16x16x32_f16(a, bfrag, acc[nt], 0, 0, 0);
        }
    }
    float dv[4];
#pragma unroll
    for (int r = 0; r < 4; ++r) dv[r] = dinv[m0 + q * 4 + r];
#pragma unroll
    for (int nt = 0; nt < 8; ++nt) {
        int col = nt * 16 + (lane & 15);
        __half* cq = C + (size_t)(col >> 5) * M * QF + (col & 31);
#pragma unroll
        for (int r = 0; r < 4; ++r)
            cq[(size_t)(m0 + q * 4 + r) * QF] = __float2half(acc[nt][r] * dv[r]);
    }
}

#define GLDS(GP, LP)                                                           \
    __builtin_amdgcn_global_load_lds(                                          \
        (const __attribute__((address_space(1))) void*)(GP),                   \
        (__attribute__((address_space(3))) void*)(LP), 16, 0, 0)

// ---- pipelined body: MFMA chunk C_ (regs C0..C3), read chunk C_+1 into
// N0..N3, issue stage C_+3 (sv SIA/SIB), load sv for C_+4 into SOA/SOB. ----
#define BODY(C_, C0, C1, C2, C3, N0, N1, N2, N3, SIA, SIB, SOA, SOB)           \
    {                                                                          \
        asm volatile("s_waitcnt lgkmcnt(4)" ::: "memory");                     \
        __builtin_amdgcn_sched_barrier(0);                                     \
        const __half* gA_ = tq + (size_t)(SIA) * QF + b8;                      \
        const __half* gB_ = tq + (size_t)(SIB) * QF + b8;                      \
        __half* LB_ = stg + ((((C_) + 3) & 3) << 10);                          \
        GLDS(gA_, LB_);                                                        \
        GLDS(gB_, LB_ + 512);                                                  \
        asm volatile("s_waitcnt vmcnt(4)" ::: "memory");                       \
        const uint32_t sva_ = sbb + 2u * (uint32_t)min(                        \
            ofs + ((C_) + 4) * 32 + e4, SIDW - 17);                            \
        const uint32_t tra_ = vaBase + ((uint32_t)(((C_) + 1) & 3) << 11);     \
        asm volatile(                                                          \
            "ds_read_u16 %0, %6\n\t"                                           \
            "ds_read_u16 %1, %6 offset:32\n\t"                                 \
            "ds_read_b64_tr_b16 %2, %7 offset:0\n\t"                           \
            "ds_read_b64_tr_b16 %3, %7 offset:1024\n\t"                        \
            "ds_read_b64_tr_b16 %4, %7 offset:32\n\t"                          \
            "ds_read_b64_tr_b16 %5, %7 offset:1056"                            \
            : "=&v"(SOA), "=&v"(SOB), "=&v"(N0), "=&v"(N1), "=&v"(N2),         \
              "=&v"(N3)                                                        \
            : "v"(sva_), "v"(tra_) : "memory");                                \
        const int eb_ = ebase + (C_) * 32;                                     \
        f16x8 af_;                                                             \
        _Pragma("unroll")                                                      \
        for (int j = 0; j < 8; ++j) {                                          \
            int m_ = eb_ + (j & 3) + ((j >> 2) << 4);                          \
            af_[j] = ((unsigned)m_ < dd) ? (_Float16)1.0f : (_Float16)0.0f;    \
        }                                                                      \
        asm volatile("s_waitcnt lgkmcnt(6)" ::: "memory");                     \
        __builtin_amdgcn_sched_barrier(0);                                     \
        f16x8 bf0_, bf1_;                                                      \
        _Pragma("unroll")                                                      \
        for (int j = 0; j < 4; ++j) {                                          \
            bf0_[j] = (C0)[j]; bf0_[j + 4] = (C1)[j];                          \
            bf1_[j] = (C2)[j]; bf1_[j + 4] = (C3)[j];                          \
        }                                                                      \
        acc0 = __builtin_amdgcn_mfma_f32_16x16x32_f16(af_, bf0_, acc0, 0, 0, 0); \
        acc1 = __builtin_amdgcn_mfma_f32_16x16x32_f16(af_, bf1_, acc1, 0, 0, 0); \
    }

// ---- grouped MFMA gather: wave = (16-node group, quarter), XCD-pinned ----
template<bool FIRST>
__global__ __launch_bounds__(256) void k_gather_mfma(
        const int* __restrict__ rs, const int* __restrict__ re,
        const ushort* __restrict__ ssrc, const float* __restrict__ dinv,
        const __half* __restrict__ t,
        const float* __restrict__ bA, const float* __restrict__ bB,
        __half* __restrict__ h, float* __restrict__ out,
        int N, int NG) {
    __shared__ __align__(16) __half  smem[4][4][1024];  // stage ring 4x2KB/wave
    __shared__ __align__(16) ushort  sidx[4][SIDW];     // ssrc 2KB/wave
    const int wave = threadIdx.x >> 6;
    const int lane = threadIdx.x & 63;
    const int x = blockIdx.x & 7;          // XCD slot (round-robin dispatch)
    const int q = x >> 1;                  // quarter pinned to XCD pair
    const int g = (((blockIdx.x >> 3) << 1) + (x & 1)) * 4 + wave;
    if (g >= NG) return;
    const int nb = g << 4;                 // first node of group
    const int e4 = lane >> 2;              // edge-in-halfchunk 0..15 (staging)
    const int b8 = (lane & 3) * 8;         // f16 offset of 16B quarter-row part
    const int col = lane & 15;
    const __half* tq = t + (size_t)q * N * QF;
    __half* stg = &smem[wave][0][0];
    ushort* sb = &sidx[wave][0];
    const uint32_t sbb = lds_addr(sb);
    const int o0 = rs[nb + col];           // node (=A row) col's edge range
    const int o1 = re[nb + col];
    const int gs = rs[nb];                 // group edge range (contiguous CSR)
    const int ge = re[nb + 15];
    const int ne = ge - gs;
    const int nc = (ne + 31) >> 5;
    const int m0 = (lane >> 4) << 2;       // A k->edge permutation base
    const int ebase = gs + m0 - o0;
    const unsigned dd = (unsigned)(o1 - o0);
    // tr-read addr, linear edge-major [32][32] (R18-verified):
    const uint32_t voff = 256u * (uint32_t)(lane >> 4)
                        + 64u * (uint32_t)((lane >> 2) & 3)
                        + 8u * (uint32_t)(lane & 3);
    const uint32_t vaBase = lds_addr(stg) + voff;
    f32x4 acc0 = {}, acc1 = {};

    const int gsa = gs & ~7;               // 16B-aligned prologue start (u16)
    const int ofs = gs - gsa;

    if (nc > 0) {
        // prologue: bulk ssrc -> LDS (512 u16 = 1KB per block instr)
        const int nblk = min((ofs + ne + SBLK - 1) / SBLK, SIDW / SBLK);
        for (int b = 0; b < nblk; ++b)
            GLDS(ssrc + gsa + b * SBLK + lane * 8, sb + b * SBLK);
        asm volatile("s_waitcnt vmcnt(0)" ::: "memory");   // ssrc resident
        // stages 0..2 (sv via C++ LDS reads; compiler-waited, queue empties)
#pragma unroll
        for (int p = 0; p < 3; ++p) {
            const int ia = min(ofs + p * 32 + e4, SIDW - 17);
            const int sA = sb[ia], sB = sb[ia + 16];
            __half* LB = stg + (p << 10);
            GLDS(tq + (size_t)sA * QF + b8, LB);
            GLDS(tq + (size_t)sB * QF + b8, LB + 512);
        }
        // initial asm: sv(3) + tr-read chunk 0  [queue: sv2 + tr4]
        uint32_t sv1A, sv1B, sv2A, sv2B;
        f16x4 RA0, RA1, RA2, RA3, RB0, RB1, RB2, RB3;
        {
            const uint32_t sva_ = sbb + 2u * (uint32_t)min(ofs + 96 + e4, SIDW - 17);
            asm volatile(
                "ds_read_u16 %0, %6\n\t"
                "ds_read_u16 %1, %6 offset:32\n\t"
                "ds_read_b64_tr_b16 %2, %7 offset:0\n\t"
                "ds_read_b64_tr_b16 %3, %7 offset:1024\n\t"
                "ds_read_b64_tr_b16 %4, %7 offset:32\n\t"
                "ds_read_b64_tr_b16 %5, %7 offset:1056"
                : "=&v"(sv1A), "=&v"(sv1B), "=&v"(RA0), "=&v"(RA1),
                  "=&v"(RA2), "=&v"(RA3)
                : "v"(sva_), "v"(vaBase) : "memory");
        }
        int c = 0;
        for (; c + 1 < nc; c += 2) {
            BODY(c,     RA0, RA1, RA2, RA3, RB0, RB1, RB2, RB3,
                 sv1A, sv1B, sv2A, sv2B);
            BODY(c + 1, RB0, RB1, RB2, RB3, RA0, RA1, RA2, RA3,
                 sv2A, sv2B, sv1A, sv1B);
        }
        if (c < nc) {   // final (even) chunk sits in RA
            asm volatile("s_waitcnt lgkmcnt(0)" ::: "memory");
            __builtin_amdgcn_sched_barrier(0);
            const int eb_ = ebase + c * 32;
            f16x8 af_;
#pragma unroll
            for (int j = 0; j < 8; ++j) {
                int m_ = eb_ + (j & 3) + ((j >> 2) << 4);
                af_[j] = ((unsigned)m_ < dd) ? (_Float16)1.0f : (_Float16)0.0f;
            }
            f16x8 bf0_, bf1_;
#pragma unroll
            for (int j = 0; j < 4; ++j) {
                bf0_[j] = RA0[j]; bf0_[j + 4] = RA1[j];
                bf1_[j] = RA2[j]; bf1_[j + 4] = RA3[j];
            }
            acc0 = __builtin_amdgcn_mfma_f32_16x16x32_f16(af_, bf0_, acc0, 0, 0, 0);
            acc1 = __builtin_amdgcn_mfma_f32_16x16x32_f16(af_, bf1_, acc1, 0, 0, 0);
        }
        asm volatile("s_waitcnt vmcnt(0)" ::: "memory");   // drain stage loads
    }
    // epilogue: D row = node-in-group = (lane>>4)*4 + reg, col = lane&15
    const int nl0 = (lane >> 4) << 2;
#pragma unroll
    for (int r2 = 0; r2 < 4; ++r2) {
        const int node = nb + nl0 + r2;
        const float di = dinv[node];
        const float s0 = __half2float(tq[(size_t)node * QF + col]);
        const float s1 = __half2float(tq[(size_t)node * QF + 16 + col]);
        float v0 = (acc0[r2] + s0) * di;
        float v1 = (acc1[r2] + s1) * di;
        if constexpr (FIRST) {
            v0 += bA[q * QF + col];
            v1 += bA[q * QF + 16 + col];
            _Float16* hp = (_Float16*)(h + (size_t)q * N * QF + (size_t)node * QF);
            __builtin_nontemporal_store((_Float16)fmaxf(v0, 0.f), hp + col);
            __builtin_nontemporal_store((_Float16)fmaxf(v1, 0.f), hp + 16 + col);
        } else {
            const float* bp = (q < 2) ? bA : bB;
            const int fb = (q & 1) * QF;
            v0 += bp[fb + col];
            v1 += bp[fb + 16 + col];
            float* op = (q < 2) ? (out + (size_t)node * F2 + fb)
                                : (out + (size_t)N * F2 + (size_t)node * F2 + fb);
            __builtin_nontemporal_store(v0, op + col);
            __builtin_nontemporal_store(v1, op + 16 + col);
        }
    }
}

extern "C" void kernel_launch(void* const* d_in, const int* in_sizes, int n_in,
                              void* d_out, int out_size, void* d_ws, size_t ws_size,
                              hipStream_t stream) {
    const float* x   = (const float*)d_in[0];
    const int*   ei  = (const int*)d_in[1];
    const float* W1  = (const float*)d_in[3];
    const float* b1  = (const float*)d_in[4];
    const float* Wmu = (const float*)d_in[5];
    const float* bmu = (const float*)d_in[6];
    const float* Wls = (const float*)d_in[7];
    const float* bls = (const float*)d_in[8];

    const int N = in_sizes[0] / IN_DIM;
    const int E = in_sizes[1] / 2;
    const int* src = ei;
    const int* dst = ei + E;
    float* out = (float*)d_out;
    const int nbuck = cdiv_i(N, BN);   // 391

    // ---- workspace carve (units: 4B slots) ----
    size_t off = 0;
    auto carve = [&](size_t n) { size_t o = off; off += (n + 3) & ~(size_t)3; return o; };
    float* ws = (float*)d_ws;
    float*  dinv   =        ws + carve(N);
    int*    rs     = (int*)(ws + carve(N));
    int*    re     = (int*)(ws + carve(N));
    int*    bcur   = (int*)(ws + carve(512));
    ushort* ssrc   = (ushort*)(ws + carve(((size_t)nbuck * CAP + 2048) / 2));
    __half* t16    = (__half*)(ws + carve((size_t)N * F1 / 2));  // [4][N][32]
    __half* h16    = (__half*)(ws + carve((size_t)N * F1 / 2));  // [4][N][32]
    __half* W1frag = (__half*)(ws + carve(8 * 8 * 64 * 8 / 2));
    __half* Wcfrag = (__half*)(ws + carve(4 * 8 * 64 * 8 / 2));
    (void)ws_size;
    // pairs (nbuck*CAP ints = 7.4MB) alias t16 (12.8MB): consumed by
    // k_bucket_build before GEMM1 writes t16.
    int* pairs = (int*)t16;
    __half* t2_16 = t16;   // GEMM2 output reuses t16 (dead after gather1)

    k_prep_frags<<<cdiv_i(8 * 8 * 64 + 4 * 8 * 64, 256), 256, 0, stream>>>(
        W1, Wmu, Wls, W1frag, Wcfrag);

    // CSR build: memset + binning + bucket_build
    hipMemsetAsync(bcur, 0, sizeof(int) * 512, stream);
    k_binning<<<cdiv_i(E, BIN_EDGES), 512, 0, stream>>>(src, dst, bcur, pairs, E);
    k_bucket_build<<<nbuck, 512, 0, stream>>>(pairs, bcur, dinv, rs, re, ssrc, N);

    const int NG = N >> 4;              // 3125 groups of 16 (N % 16 == 0)
    const int NBI = cdiv_i(NG, 8);      // block-octets: grid divisible by 8

    // GEMM1 (MFMA): t16 = fp16(dinv * (x @ W1)), quarter-split layout
    k_gemm1_mfma<<<cdiv_i(N, 64), 256, 0, stream>>>(x, W1frag, dinv, t16, N);
    // conv1 aggregate (pipelined MFMA-gather, XCD-pinned) + bias + relu -> h16
    k_gather_mfma<true><<<8 * NBI, 256, 0, stream>>>(
        rs, re, ssrc, dinv, t16, b1, b1, h16, out, N, NG);
    // GEMM2 (MFMA): t2 = fp16(dinv * (h @ Wcat)), quarter-split
    k_gemm2_mfma<<<cdiv_i(N, 64), 256, 0, stream>>>(h16, Wcfrag, dinv, t2_16, N);
    // conv2 aggregate (pipelined MFMA-gather, XCD-pinned) -> out (mu||logstd)
    k_gather_mfma<false><<<8 * NBI, 256, 0, stream>>>(
        rs, re, ssrc, dinv, t2_16, bmu, bls, h16, out, N, NG);
}